// Round 1
// baseline (835.711 us; speedup 1.0000x reference)
//
#include <hip/hip_runtime.h>

#define NDIM 8192
#define THREADS 256
#define V4_PER_THREAD (NDIM / 4 / THREADS)  // 8

__global__ __launch_bounds__(THREADS) void bitransition_kernel(
    const float* __restrict__ g0, const float* __restrict__ g1,
    float* __restrict__ out0, float* __restrict__ out1)
{
    const int row = blockIdx.x;
    const int tid = threadIdx.x;
    const size_t base = (size_t)row * NDIM;

    const float4* __restrict__ g0v = (const float4*)(g0 + base);
    const float4* __restrict__ g1v = (const float4*)(g1 + base);
    float4* __restrict__ o0v = (float4*)(out0 + base);
    float4* __restrict__ o1v = (float4*)(out1 + base);

    // Load this row of graph1 into registers, accumulate partial sum.
    float4 v[V4_PER_THREAD];
    float sum = 0.f;
#pragma unroll
    for (int i = 0; i < V4_PER_THREAD; ++i) {
        v[i] = g1v[tid + i * THREADS];
        sum += (v[i].x + v[i].y) + (v[i].z + v[i].w);
    }

    // Copy graph0's row while the reduction dependencies resolve.
#pragma unroll
    for (int i = 0; i < V4_PER_THREAD; ++i) {
        o0v[tid + i * THREADS] = g0v[tid + i * THREADS];
    }

    // Wave (64-lane) reduction, then cross-wave via tiny LDS.
#pragma unroll
    for (int off = 32; off > 0; off >>= 1)
        sum += __shfl_down(sum, off, 64);

    __shared__ float wsum[THREADS / 64];
    const int lane = tid & 63;
    const int wid = tid >> 6;
    if (lane == 0) wsum[wid] = sum;
    __syncthreads();
    float total = 0.f;
#pragma unroll
    for (int w = 0; w < THREADS / 64; ++w) total += wsum[w];

    const float inv = 1.0f / total;

#pragma unroll
    for (int i = 0; i < V4_PER_THREAD; ++i) {
        float4 r;
        r.x = v[i].x * inv;
        r.y = v[i].y * inv;
        r.z = v[i].z * inv;
        r.w = v[i].w * inv;
        o1v[tid + i * THREADS] = r;
    }
}

extern "C" void kernel_launch(void* const* d_in, const int* in_sizes, int n_in,
                              void* d_out, int out_size, void* d_ws, size_t ws_size,
                              hipStream_t stream) {
    const float* g0 = (const float*)d_in[0];
    const float* g1 = (const float*)d_in[1];
    float* out0 = (float*)d_out;                          // graph0 passthrough
    float* out1 = (float*)d_out + (size_t)NDIM * NDIM;    // normalized graph1

    bitransition_kernel<<<NDIM, THREADS, 0, stream>>>(g0, g1, out0, out1);
}